// Round 1
// baseline (277.932 us; speedup 1.0000x reference)
//
#include <hip/hip_runtime.h>
#include <hip/hip_fp16.h>

#define N_NODES 100000
#define N_EDGES 1600000
#define N_GRAPHS 512
#define FEAT 128
#define EMB 32
#define ZROW N_NODES                        // dedicated zero row for padding
#define PADCAP (N_EDGES + 8 * N_NODES)      // pad8 worst-case col slots
#define NCOPY 64                            // privatized pool accumulator copies
#define NBKT 250                            // dst buckets (400 nodes each)
#define NPB 400                             // nodes per bucket
#define ABLK 1024                           // bin phase blocks
#define EPB 1563                            // ceil(N_EDGES / ABLK)
#define NTILE (N_NODES / 16)                // 6250 MFMA row tiles
#define ABHALF (N_NODES / 8)                // 12500 blocks per feature-half pass
#define HSTRIDE ((size_t)(N_NODES + 1) * 16)  // half-table stride in u16

typedef unsigned short u16;
typedef unsigned int u32;
typedef _Float16 f16;
typedef float f32x4 __attribute__((ext_vector_type(4)));
typedef unsigned short u16x4 __attribute__((ext_vector_type(4)));
typedef f16 f16x8 __attribute__((ext_vector_type(8)));

__device__ __forceinline__ int pad8(int d) { return (d + 7) & ~7; }

__device__ __forceinline__ float4 h4_to_f4(u16x4 v) {
  union { unsigned int u; __half2 h; } a, b;
  a.u = (unsigned int)v.x | ((unsigned int)v.y << 16);
  b.u = (unsigned int)v.z | ((unsigned int)v.w << 16);
  float2 f0 = __half22float2(a.h);
  float2 f1 = __half22float2(b.h);
  return make_float4(f0.x, f0.y, f1.x, f1.y);
}

__device__ __forceinline__ u16x4 f4_to_h4(float4 f) {
  union { unsigned int u; __half2 h; } a, b;
  a.h = __float22half2_rn(make_float2(f.x, f.y));
  b.h = __float22half2_rn(make_float2(f.z, f.w));
  u16x4 r;
  r.x = (u16)(a.u & 0xffff); r.y = (u16)(a.u >> 16);
  r.z = (u16)(b.u & 0xffff); r.w = (u16)(b.u >> 16);
  return r;
}

// ---------------- misc ----------------

__global__ __launch_bounds__(256) void k_node_init(const int* __restrict__ degcnt,
                                                   float* __restrict__ dis,
                                                   u16* __restrict__ hs1) {
  int i = blockIdx.x * 256 + threadIdx.x;
  if (i < N_NODES) dis[i] = rsqrtf((float)degcnt[i] + 1.0f);
  if (i < 16) {                               // zero row in BOTH half-tables
    hs1[(size_t)ZROW * 16 + i] = 0;
    hs1[HSTRIDE + (size_t)ZROW * 16 + i] = 0;
  }
}

__global__ __launch_bounds__(512) void k_gcnt(const int* __restrict__ batch,
                                              int* __restrict__ gcnt) {
  __shared__ int first[N_GRAPHS + 1];
  int g = threadIdx.x;
  int lo = 0, hi = N_NODES;
  while (lo < hi) {
    int mid = (lo + hi) >> 1;
    if (batch[mid] < g) lo = mid + 1; else hi = mid;
  }
  first[g] = lo;
  if (g == 0) first[N_GRAPHS] = N_NODES;
  __syncthreads();
  gcnt[g] = first[g + 1] - first[g];
}

// ---------------- row_ptr scans (over pad8(deg)) ----------------

__global__ __launch_bounds__(256) void k_scanA(const int* __restrict__ degcnt,
                                               int* __restrict__ blocksum) {
  __shared__ int sh[256];
  int t = threadIdx.x;
  int base = blockIdx.x * 1024;
  int s = 0;
#pragma unroll
  for (int j = 0; j < 4; j++) {
    int idx = base + t * 4 + j;
    if (idx < N_NODES) s += pad8(degcnt[idx]);
  }
  sh[t] = s;
  __syncthreads();
  for (int off = 128; off > 0; off >>= 1) {
    if (t < off) sh[t] += sh[t + off];
    __syncthreads();
  }
  if (t == 0) blocksum[blockIdx.x] = sh[0];
}

__global__ __launch_bounds__(128) void k_scanB(const int* __restrict__ blocksum,
                                               int* __restrict__ blockoff,
                                               int* __restrict__ total_out, int nb) {
  __shared__ int sh[128];
  int t = threadIdx.x;
  int v = (t < nb) ? blocksum[t] : 0;
  sh[t] = v;
  __syncthreads();
  for (int off = 1; off < 128; off <<= 1) {
    int add = (t >= off) ? sh[t - off] : 0;
    __syncthreads();
    sh[t] += add;
    __syncthreads();
  }
  if (t < nb) blockoff[t] = sh[t] - v;   // exclusive
  if (t == nb - 1) total_out[0] = sh[t];
}

__global__ __launch_bounds__(256) void k_scanC(const int* __restrict__ degcnt,
                                               const int* __restrict__ blockoff,
                                               int* __restrict__ row_ptr) {
  __shared__ int sh[256];
  int t = threadIdx.x;
  int base = blockIdx.x * 1024;
  int v[4];
#pragma unroll
  for (int j = 0; j < 4; j++) {
    int idx = base + t * 4 + j;
    v[j] = (idx < N_NODES) ? pad8(degcnt[idx]) : 0;
  }
  int tsum = v[0] + v[1] + v[2] + v[3];
  sh[t] = tsum;
  __syncthreads();
  for (int off = 1; off < 256; off <<= 1) {
    int add = (t >= off) ? sh[t - off] : 0;
    __syncthreads();
    sh[t] += add;
    __syncthreads();
  }
  int p = sh[t] - tsum + blockoff[blockIdx.x];
#pragma unroll
  for (int j = 0; j < 4; j++) {
    int idx = base + t * 4 + j;
    if (idx < N_NODES) row_ptr[idx] = p;
    p += v[j];
  }
}

// ---------------- two-phase binned CSR fill (also produces degcnt) ----------------

__global__ __launch_bounds__(256) void k_binA(const int* __restrict__ dst,
                                              int* __restrict__ cnt) {
  __shared__ int h[NBKT];
  int k = blockIdx.x, t = threadIdx.x;
  for (int i = t; i < NBKT; i += 256) h[i] = 0;
  __syncthreads();
  int e0 = k * EPB;
  int e1 = min(e0 + EPB, N_EDGES);
  for (int e = e0 + t; e < e1; e += 256)
    atomicAdd(&h[(u32)dst[e] / (u32)NPB], 1);
  __syncthreads();
  for (int i = t; i < NBKT; i += 256) cnt[k * NBKT + i] = h[i];
}

__global__ __launch_bounds__(256) void k_binscanA(const int* __restrict__ cnt,
                                                  int* __restrict__ off,
                                                  int* __restrict__ tot) {
  __shared__ int sh[256];
  int b = blockIdx.x, t = threadIdx.x;
  int v[4];
#pragma unroll
  for (int j = 0; j < 4; j++) v[j] = cnt[(t * 4 + j) * NBKT + b];
  int tsum = v[0] + v[1] + v[2] + v[3];
  sh[t] = tsum;
  __syncthreads();
  for (int o = 1; o < 256; o <<= 1) {
    int add = (t >= o) ? sh[t - o] : 0;
    __syncthreads();
    sh[t] += add;
    __syncthreads();
  }
  int p = sh[t] - tsum;
#pragma unroll
  for (int j = 0; j < 4; j++) {
    off[(t * 4 + j) * NBKT + b] = p;
    p += v[j];
  }
  if (t == 255) tot[b] = p;
}

__global__ __launch_bounds__(256) void k_binscanB(const int* __restrict__ tot,
                                                  int* __restrict__ base) {
  __shared__ int sh[256];
  int t = threadIdx.x;
  int v = (t < NBKT) ? tot[t] : 0;
  sh[t] = v;
  __syncthreads();
  for (int o = 1; o < 256; o <<= 1) {
    int add = (t >= o) ? sh[t - o] : 0;
    __syncthreads();
    sh[t] += add;
    __syncthreads();
  }
  if (t < NBKT) base[t] = sh[t] - v;
  if (t == NBKT - 1) base[NBKT] = sh[t];
}

__global__ __launch_bounds__(256) void k_binscat(const int* __restrict__ src,
                                                 const int* __restrict__ dst,
                                                 const int* __restrict__ off,
                                                 const int* __restrict__ base,
                                                 u32* __restrict__ binbuf) {
  __shared__ int posB[NBKT];
  __shared__ int h[NBKT];
  int k = blockIdx.x, t = threadIdx.x;
  for (int i = t; i < NBKT; i += 256) {
    posB[i] = base[i] + off[k * NBKT + i];
    h[i] = 0;
  }
  __syncthreads();
  int e0 = k * EPB;
  int e1 = min(e0 + EPB, N_EDGES);
  for (int e = e0 + t; e < e1; e += 256) {
    u32 d = (u32)dst[e];
    int b = d / (u32)NPB;
    int r = atomicAdd(&h[b], 1);
    binbuf[posB[b] + r] = (u32)src[e] * (u32)NPB + (d - (u32)b * NPB);
  }
}

__global__ __launch_bounds__(256) void k_bdeg(const u32* __restrict__ binbuf,
                                              const int* __restrict__ base,
                                              int* __restrict__ degcnt) {
  __shared__ int c[NPB];
  int b = blockIdx.x, t = threadIdx.x;
  for (int i = t; i < NPB; i += 256) c[i] = 0;
  __syncthreads();
  int s0 = base[b], s1 = base[b + 1];
  for (int i = s0 + t; i < s1; i += 256) {
    u32 p = binbuf[i];
    u32 s = p / (u32)NPB;
    atomicAdd(&c[p - s * (u32)NPB], 1);
  }
  __syncthreads();
  for (int i = t; i < NPB; i += 256) degcnt[b * NPB + i] = c[i];
}

__global__ __launch_bounds__(256) void k_fillB(const u32* __restrict__ binbuf,
                                               const int* __restrict__ base,
                                               const int* __restrict__ row_ptr,
                                               int* __restrict__ col) {
  __shared__ int rp[NPB + 1];
  __shared__ int cur[NPB];
  int b = blockIdx.x, t = threadIdx.x;
  for (int i = t; i < NPB + 1; i += 256) rp[i] = row_ptr[b * NPB + i];
  for (int i = t; i < NPB; i += 256) cur[i] = 0;
  __syncthreads();
  int s0 = base[b], s1 = base[b + 1];
  for (int i = s0 + t; i < s1; i += 256) {
    u32 p = binbuf[i];
    u32 s = p / (u32)NPB;
    int ld = p - s * (u32)NPB;
    int pos = atomicAdd(&cur[ld], 1);
    col[rp[ld] + pos] = (int)s;
  }
  __syncthreads();
  for (int ld = t; ld < NPB; ld += 256) {
    int bs = rp[ld], len = rp[ld + 1] - bs, c = cur[ld];
    for (int j = c; j < len; j++) col[bs + j] = ZROW;
  }
}

// ---------------- GEMMs via MFMA 16x16x32 f16 (W in register B-frags) ----------------
// Output layout is now SPLIT: hs[2][N_NODES+1][16] f16 — half-table h holds dims
// h*16..h*16+15 for every node, contiguous (3.2 MB per half -> fits per-XCD L2).

__global__ __launch_bounds__(256) void k_gemm1(const float* __restrict__ x,
                                               const float* __restrict__ W1,
                                               const float* __restrict__ dis,
                                               u16* __restrict__ hs1) {
  int wid = (blockIdx.x * 256 + threadIdx.x) >> 6;   // wave id = 16-row tile
  if (wid >= NTILE) return;
  int l = threadIdx.x & 63;
  int m = l & 15, q = l >> 4;
  f16x8 B[4][2];
#pragma unroll
  for (int s = 0; s < 4; ++s)
#pragma unroll
    for (int h = 0; h < 2; ++h)
#pragma unroll
      for (int j = 0; j < 8; ++j)
        B[s][h][j] = (f16)W1[(s * 32 + q * 8 + j) * EMB + h * 16 + m];
  int row = wid * 16 + m;
  const float* xr = x + (size_t)row * FEAT + q * 8;
  f32x4 acc0 = {0.f, 0.f, 0.f, 0.f}, acc1 = {0.f, 0.f, 0.f, 0.f};
#pragma unroll
  for (int s = 0; s < 4; ++s) {
    f32x4 xa = __builtin_nontemporal_load((const f32x4*)(xr + s * 32));
    f32x4 xb = __builtin_nontemporal_load((const f32x4*)(xr + s * 32 + 4));
    f16x8 A;
    A[0] = (f16)xa.x; A[1] = (f16)xa.y; A[2] = (f16)xa.z; A[3] = (f16)xa.w;
    A[4] = (f16)xb.x; A[5] = (f16)xb.y; A[6] = (f16)xb.z; A[7] = (f16)xb.w;
    acc0 = __builtin_amdgcn_mfma_f32_16x16x32_f16(A, B[s][0], acc0, 0, 0, 0);
    acc1 = __builtin_amdgcn_mfma_f32_16x16x32_f16(A, B[s][1], acc1, 0, 0, 0);
  }
  f32x4 dq = *(const f32x4*)(dis + wid * 16 + q * 4);
  u16* oL = hs1 + (size_t)(wid * 16) * 16;
  u16* oH = hs1 + HSTRIDE + (size_t)(wid * 16) * 16;
#pragma unroll
  for (int i = 0; i < 4; ++i) {
    int r = q * 4 + i;
    float dv = (i == 0) ? dq.x : (i == 1) ? dq.y : (i == 2) ? dq.z : dq.w;
    oL[(size_t)r * 16 + m] = __half_as_ushort(__float2half_rn(acc0[i] * dv));
    oH[(size_t)r * 16 + m] = __half_as_ushort(__float2half_rn(acc1[i] * dv));
  }
}

__global__ __launch_bounds__(256) void k_gemm2(const u16* __restrict__ in1,
                                               const float* __restrict__ W2,
                                               const float* __restrict__ dis,
                                               u16* __restrict__ hs2) {
  int wid = (blockIdx.x * 256 + threadIdx.x) >> 6;
  if (wid >= NTILE) return;
  int l = threadIdx.x & 63;
  int m = l & 15, q = l >> 4;
  f16x8 B[2];
#pragma unroll
  for (int h = 0; h < 2; ++h)
#pragma unroll
    for (int j = 0; j < 8; ++j)
      B[h][j] = (f16)W2[(q * 8 + j) * EMB + h * 16 + m];
  int row = wid * 16 + m;
  // input row dims q*8..q*8+7 live in half-table (q>>1) at offset (q&1)*8
  const u16* ap = in1 + (size_t)(q >> 1) * HSTRIDE + (size_t)row * 16 + (q & 1) * 8;
  f16x8 A = *(const f16x8*)ap;
  f32x4 acc0 = {0.f, 0.f, 0.f, 0.f}, acc1 = {0.f, 0.f, 0.f, 0.f};
  acc0 = __builtin_amdgcn_mfma_f32_16x16x32_f16(A, B[0], acc0, 0, 0, 0);
  acc1 = __builtin_amdgcn_mfma_f32_16x16x32_f16(A, B[1], acc1, 0, 0, 0);
  f32x4 dq = *(const f32x4*)(dis + wid * 16 + q * 4);
  u16* oL = hs2 + (size_t)(wid * 16) * 16;
  u16* oH = hs2 + HSTRIDE + (size_t)(wid * 16) * 16;
#pragma unroll
  for (int i = 0; i < 4; ++i) {
    int r = q * 4 + i;
    float dv = (i == 0) ? dq.x : (i == 1) ? dq.y : (i == 2) ? dq.z : dq.w;
    oL[(size_t)r * 16 + m] = __half_as_ushort(__float2half_rn(acc0[i] * dv));
    oH[(size_t)r * 16 + m] = __half_as_ushort(__float2half_rn(acc1[i] * dv));
  }
}

// ---------------- Aggregation: feature-dim split into two L2-resident passes ----------------
// R12 PMC: agg at 1.8 TB/s L2-miss BW -> the 6.4 MB gather table does not fit the
// 4 MB per-XCD L2 (~40% capacity misses to L3 at 128B lines). Split the feature dim:
// each pass gathers 32 B/edge from a contiguous 3.2 MB half-table that fully fits
// in every XCD's L2. Grid = 2*ABHALF; low blocks do half 0, high blocks half 1
// (dispatch-order temporal separation). Lanes 0-31 own node0, 32-63 own node1;
// 8 groups x 4 lanes per node; 4-deep chunk unroll keeps 8 loads in flight/lane.

__device__ __forceinline__ float4 agg_half(const u16* __restrict__ tab,
                                           const int* __restrict__ row_ptr,
                                           const int* __restrict__ col,
                                           int node, int g, int sub) {
  const u16x4* t4 = (const u16x4*)tab;
  int a0 = row_ptr[node];
  int na = (row_ptr[node + 1] - a0) >> 3;     // 8-slot chunks
  int ec = a0 + g;
  float4 A = make_float4(0.f, 0.f, 0.f, 0.f);
  int s0 = (0 < na) ? __builtin_nontemporal_load(&col[ec])      : ZROW;
  int s1 = (1 < na) ? __builtin_nontemporal_load(&col[ec + 8])  : ZROW;
  int s2 = (2 < na) ? __builtin_nontemporal_load(&col[ec + 16]) : ZROW;
  int s3 = (3 < na) ? __builtin_nontemporal_load(&col[ec + 24]) : ZROW;
  for (int i = 0; i < na; i += 4) {
    u16x4 v0 = t4[(size_t)s0 * 4 + sub];
    u16x4 v1 = t4[(size_t)s1 * 4 + sub];
    u16x4 v2 = t4[(size_t)s2 * 4 + sub];
    u16x4 v3 = t4[(size_t)s3 * 4 + sub];
    s0 = (i + 4 < na) ? __builtin_nontemporal_load(&col[ec + (i + 4) * 8]) : ZROW;
    s1 = (i + 5 < na) ? __builtin_nontemporal_load(&col[ec + (i + 5) * 8]) : ZROW;
    s2 = (i + 6 < na) ? __builtin_nontemporal_load(&col[ec + (i + 6) * 8]) : ZROW;
    s3 = (i + 7 < na) ? __builtin_nontemporal_load(&col[ec + (i + 7) * 8]) : ZROW;
    float4 f0 = h4_to_f4(v0), f1 = h4_to_f4(v1);
    float4 f2 = h4_to_f4(v2), f3 = h4_to_f4(v3);
    A.x += (f0.x + f1.x) + (f2.x + f3.x);
    A.y += (f0.y + f1.y) + (f2.y + f3.y);
    A.z += (f0.z + f1.z) + (f2.z + f3.z);
    A.w += (f0.w + f1.w) + (f2.w + f3.w);
  }
  // reduce across the node's 8 groups (within the 32-lane half-wave)
#pragma unroll
  for (int mm = 4; mm < 32; mm <<= 1) {
    A.x += __shfl_xor(A.x, mm); A.y += __shfl_xor(A.y, mm);
    A.z += __shfl_xor(A.z, mm); A.w += __shfl_xor(A.w, mm);
  }
  // self-loop contribution (row pre-scaled by dis[node])
  float4 s = h4_to_f4(t4[(size_t)node * 4 + sub]);
  A.x += s.x; A.y += s.y; A.z += s.z; A.w += s.w;
  return A;
}

__device__ __forceinline__ float4 relu_row(float4 acc, float d, float4 bq) {
  float4 o;
  o.x = fmaxf(fmaf(acc.x, d, bq.x), 0.f);
  o.y = fmaxf(fmaf(acc.y, d, bq.y), 0.f);
  o.z = fmaxf(fmaf(acc.z, d, bq.z), 0.f);
  o.w = fmaxf(fmaf(acc.w, d, bq.w), 0.f);
  return o;
}

__global__ __launch_bounds__(256) void k_agg1(const u16* __restrict__ hs,
                                              const int* __restrict__ row_ptr,
                                              const int* __restrict__ col,
                                              const float* __restrict__ dis,
                                              const float* __restrict__ b,
                                              u16* __restrict__ out) {
  int t = threadIdx.x;
  int wv = t >> 6, l = t & 63;
  int bid = blockIdx.x;
  int half = (bid >= ABHALF) ? 1 : 0;
  int nb = bid - half * ABHALF;
  int node = nb * 8 + wv * 2 + (l >> 5);
  int g = (l >> 2) & 7, sub = l & 3;
  const u16* tab = hs + (size_t)half * HSTRIDE;
  float4 A = agg_half(tab, row_ptr, col, node, g, sub);
  if ((l & 31) < 4) {
    float4 bq = ((const float4*)b)[half * 4 + sub];
    float4 o = relu_row(A, dis[node], bq);
    u16x4* dstp = (u16x4*)(out + (size_t)half * HSTRIDE + (size_t)node * 16);
    __builtin_nontemporal_store(f4_to_h4(o), &dstp[sub]);
  }
}

__global__ __launch_bounds__(256) void k_agg2pool(const u16* __restrict__ hs,
                                                  const int* __restrict__ row_ptr,
                                                  const int* __restrict__ col,
                                                  const float* __restrict__ dis,
                                                  const float* __restrict__ b2,
                                                  const float* __restrict__ Wo,
                                                  const int* __restrict__ batch,
                                                  float* __restrict__ gaccP) {
  int t = threadIdx.x;
  int wv = t >> 6, l = t & 63;
  int bid = blockIdx.x;
  int half = (bid >= ABHALF) ? 1 : 0;
  int nb = bid - half * ABHALF;
  int node = nb * 8 + wv * 2 + (l >> 5);
  int g = (l >> 2) & 7, sub = l & 3;
  const u16* tab = hs + (size_t)half * HSTRIDE;
  float4 A = agg_half(tab, row_ptr, col, node, g, sub);
  float4 bq = ((const float4*)b2)[half * 4 + sub];
  float4 wq = ((const float4*)Wo)[half * 4 + sub];
  float4 o = relu_row(A, dis[node], bq);
  float p = o.x * wq.x + o.y * wq.y + o.z * wq.z + o.w * wq.w;
  p += __shfl_xor(p, 1);
  p += __shfl_xor(p, 2);
  int copy = bid & (NCOPY - 1);
  if ((l & 31) == 0) atomicAdd(&gaccP[copy * N_GRAPHS + batch[node]], p);
}

__global__ __launch_bounds__(256) void k_finalize(const float* __restrict__ gaccP,
                                                  const int* __restrict__ gcnt,
                                                  const float* __restrict__ bo,
                                                  float* __restrict__ out) {
  int g = blockIdx.x * 256 + threadIdx.x;
  if (g < N_GRAPHS) {
    float s = 0.f;
#pragma unroll 8
    for (int c = 0; c < NCOPY; ++c) s += gaccP[c * N_GRAPHS + g];
    out[g] = s / fmaxf((float)gcnt[g], 1.0f) + bo[0];
  }
}

// ---------------- launch ----------------

extern "C" void kernel_launch(void* const* d_in, const int* in_sizes, int n_in,
                              void* d_out, int out_size, void* d_ws, size_t ws_size,
                              hipStream_t stream) {
  const float* x     = (const float*)d_in[0];
  const int*   ei    = (const int*)d_in[1];   // [2, E]: src then dst
  const int*   batch = (const int*)d_in[2];
  const float* W1    = (const float*)d_in[3];
  const float* b1    = (const float*)d_in[4];
  const float* W2    = (const float*)d_in[5];
  const float* b2    = (const float*)d_in[6];
  const float* Wo    = (const float*)d_in[7];
  const float* bo    = (const float*)d_in[8];
  float* out = (float*)d_out;

  const int* src = ei;
  const int* dst = ei + N_EDGES;

  char* w = (char*)d_ws;
  float* gaccP   = (float*)w;  w += (size_t)NCOPY * N_GRAPHS * 4;   // zeroed
  size_t zero_bytes = (size_t)(w - (char*)d_ws);
  int*   degcnt  = (int*)w;    w += (size_t)N_NODES * 4;            // written by k_bdeg
  int*   gcnt    = (int*)w;    w += (size_t)N_GRAPHS * 4;
  int*   row_ptr = (int*)w;    w += (size_t)(N_NODES + 4) * 4;
  int*   blocksum= (int*)w;    w += 128 * 4;
  int*   blockoff= (int*)w;    w += 128 * 4;
  int*   cnt     = (int*)w;    w += (size_t)ABLK * NBKT * 4;        // 1.0 MB
  int*   boff    = (int*)w;    w += (size_t)ABLK * NBKT * 4;        // 1.0 MB
  int*   btot    = (int*)w;    w += (size_t)(NBKT + 8) * 4;
  int*   bbase   = (int*)w;    w += (size_t)(NBKT + 8) * 4;
  int*   col     = (int*)w;    w += (size_t)PADCAP * 4;
  float* dis     = (float*)w;  w += (size_t)N_NODES * 4;
  u16*   hs1     = (u16*)w;    w += (size_t)(N_NODES + 1) * EMB * 2;  // [2][N+1][16] f16
  u16*   out1    = (u16*)w;    w += (size_t)(N_NODES + 1) * EMB * 2;  // [2][N+1][16] f16
  u32*   binbuf  = (u32*)out1;  // alias: binbuf (6.4MB) dead before agg1 writes out1
  u16*   hs2     = hs1;         // hs1 dead after agg1; zero rows persist

  const int NB  = (N_NODES + 255) / 256;    // 391
  const int SB  = (N_NODES + 1023) / 1024;  // 98
  const int GB  = (NTILE * 64 + 255) / 256; // 1563 MFMA blocks
  const int ABG = 2 * ABHALF;               // 25000: two feature-half passes

  (void)hipMemsetAsync(d_ws, 0, zero_bytes, stream);

  // bin pipeline (produces binbuf + degree histogram)
  k_binA<<<ABLK, 256, 0, stream>>>(dst, cnt);
  k_binscanA<<<NBKT, 256, 0, stream>>>(cnt, boff, btot);
  k_binscanB<<<1, 256, 0, stream>>>(btot, bbase);
  k_binscat<<<ABLK, 256, 0, stream>>>(src, dst, boff, bbase, binbuf);
  k_bdeg<<<NBKT, 256, 0, stream>>>(binbuf, bbase, degcnt);

  k_node_init<<<NB, 256, 0, stream>>>(degcnt, dis, hs1);
  k_gcnt<<<1, 512, 0, stream>>>(batch, gcnt);
  k_scanA<<<SB, 256, 0, stream>>>(degcnt, blocksum);
  k_scanB<<<1, 128, 0, stream>>>(blocksum, blockoff, row_ptr + N_NODES, SB);
  k_scanC<<<SB, 256, 0, stream>>>(degcnt, blockoff, row_ptr);
  k_fillB<<<NBKT, 256, 0, stream>>>(binbuf, bbase, row_ptr, col);

  k_gemm1<<<GB, 256, 0, stream>>>(x, W1, dis, hs1);
  k_agg1<<<ABG, 256, 0, stream>>>(hs1, row_ptr, col, dis, b1, out1);
  k_gemm2<<<GB, 256, 0, stream>>>(out1, W2, dis, hs2);
  k_agg2pool<<<ABG, 256, 0, stream>>>(hs2, row_ptr, col, dis, b2, Wo, batch, gaccP);
  k_finalize<<<2, 256, 0, stream>>>(gaccP, gcnt, bo, out);
}

// Round 2
// 247.137 us; speedup vs baseline: 1.1246x; 1.1246x over previous
//
#include <hip/hip_runtime.h>
#include <hip/hip_fp16.h>

#define N_NODES 100000
#define N_EDGES 1600000
#define N_GRAPHS 512
#define FEAT 128
#define EMB 32
#define ZROW N_NODES                        // dedicated zero row for padding
#define PADCAP (N_EDGES + 8 * N_NODES)      // pad8 worst-case col slots
#define NCOPY 64                            // privatized pool accumulator copies
#define NBKT 250                            // dst buckets (400 nodes each)
#define NPB 400                             // nodes per bucket
#define ABLK 1024                           // bin phase blocks
#define EPB 1563                            // ceil(N_EDGES / ABLK)
#define NTILE (N_NODES / 16)                // 6250 MFMA row tiles
#define AGB (N_NODES / 32)                  // 3125 agg blocks (32 nodes/block, 8/wave)

typedef unsigned short u16;
typedef unsigned int u32;
typedef _Float16 f16;
typedef float f32x4 __attribute__((ext_vector_type(4)));
typedef unsigned short u16x4 __attribute__((ext_vector_type(4)));
typedef f16 f16x8 __attribute__((ext_vector_type(8)));

__device__ __forceinline__ int pad8(int d) { return (d + 7) & ~7; }

__device__ __forceinline__ float4 h4_to_f4(u16x4 v) {
  union { unsigned int u; __half2 h; } a, b;
  a.u = (unsigned int)v.x | ((unsigned int)v.y << 16);
  b.u = (unsigned int)v.z | ((unsigned int)v.w << 16);
  float2 f0 = __half22float2(a.h);
  float2 f1 = __half22float2(b.h);
  return make_float4(f0.x, f0.y, f1.x, f1.y);
}

__device__ __forceinline__ u16x4 f4_to_h4(float4 f) {
  union { unsigned int u; __half2 h; } a, b;
  a.h = __float22half2_rn(make_float2(f.x, f.y));
  b.h = __float22half2_rn(make_float2(f.z, f.w));
  u16x4 r;
  r.x = (u16)(a.u & 0xffff); r.y = (u16)(a.u >> 16);
  r.z = (u16)(b.u & 0xffff); r.w = (u16)(b.u >> 16);
  return r;
}

// ---------------- misc ----------------

__global__ __launch_bounds__(256) void k_node_init(const int* __restrict__ degcnt,
                                                   float* __restrict__ dis,
                                                   u16* __restrict__ hs1) {
  int i = blockIdx.x * 256 + threadIdx.x;
  if (i < N_NODES) dis[i] = rsqrtf((float)degcnt[i] + 1.0f);
  if (i < EMB) hs1[(size_t)ZROW * EMB + i] = 0;
}

__global__ __launch_bounds__(512) void k_gcnt(const int* __restrict__ batch,
                                              int* __restrict__ gcnt) {
  __shared__ int first[N_GRAPHS + 1];
  int g = threadIdx.x;
  int lo = 0, hi = N_NODES;
  while (lo < hi) {
    int mid = (lo + hi) >> 1;
    if (batch[mid] < g) lo = mid + 1; else hi = mid;
  }
  first[g] = lo;
  if (g == 0) first[N_GRAPHS] = N_NODES;
  __syncthreads();
  gcnt[g] = first[g + 1] - first[g];
}

// ---------------- row_ptr scans (over pad8(deg)) ----------------

__global__ __launch_bounds__(256) void k_scanA(const int* __restrict__ degcnt,
                                               int* __restrict__ blocksum) {
  __shared__ int sh[256];
  int t = threadIdx.x;
  int base = blockIdx.x * 1024;
  int s = 0;
#pragma unroll
  for (int j = 0; j < 4; j++) {
    int idx = base + t * 4 + j;
    if (idx < N_NODES) s += pad8(degcnt[idx]);
  }
  sh[t] = s;
  __syncthreads();
  for (int off = 128; off > 0; off >>= 1) {
    if (t < off) sh[t] += sh[t + off];
    __syncthreads();
  }
  if (t == 0) blocksum[blockIdx.x] = sh[0];
}

__global__ __launch_bounds__(128) void k_scanB(const int* __restrict__ blocksum,
                                               int* __restrict__ blockoff,
                                               int* __restrict__ total_out, int nb) {
  __shared__ int sh[128];
  int t = threadIdx.x;
  int v = (t < nb) ? blocksum[t] : 0;
  sh[t] = v;
  __syncthreads();
  for (int off = 1; off < 128; off <<= 1) {
    int add = (t >= off) ? sh[t - off] : 0;
    __syncthreads();
    sh[t] += add;
    __syncthreads();
  }
  if (t < nb) blockoff[t] = sh[t] - v;   // exclusive
  if (t == nb - 1) total_out[0] = sh[t];
}

__global__ __launch_bounds__(256) void k_scanC(const int* __restrict__ degcnt,
                                               const int* __restrict__ blockoff,
                                               int* __restrict__ row_ptr) {
  __shared__ int sh[256];
  int t = threadIdx.x;
  int base = blockIdx.x * 1024;
  int v[4];
#pragma unroll
  for (int j = 0; j < 4; j++) {
    int idx = base + t * 4 + j;
    v[j] = (idx < N_NODES) ? pad8(degcnt[idx]) : 0;
  }
  int tsum = v[0] + v[1] + v[2] + v[3];
  sh[t] = tsum;
  __syncthreads();
  for (int off = 1; off < 256; off <<= 1) {
    int add = (t >= off) ? sh[t - off] : 0;
    __syncthreads();
    sh[t] += add;
    __syncthreads();
  }
  int p = sh[t] - tsum + blockoff[blockIdx.x];
#pragma unroll
  for (int j = 0; j < 4; j++) {
    int idx = base + t * 4 + j;
    if (idx < N_NODES) row_ptr[idx] = p;
    p += v[j];
  }
}

// ---------------- two-phase binned CSR fill (also produces degcnt) ----------------

__global__ __launch_bounds__(256) void k_binA(const int* __restrict__ dst,
                                              int* __restrict__ cnt) {
  __shared__ int h[NBKT];
  int k = blockIdx.x, t = threadIdx.x;
  for (int i = t; i < NBKT; i += 256) h[i] = 0;
  __syncthreads();
  int e0 = k * EPB;
  int e1 = min(e0 + EPB, N_EDGES);
  for (int e = e0 + t; e < e1; e += 256)
    atomicAdd(&h[(u32)dst[e] / (u32)NPB], 1);
  __syncthreads();
  for (int i = t; i < NBKT; i += 256) cnt[k * NBKT + i] = h[i];
}

__global__ __launch_bounds__(256) void k_binscanA(const int* __restrict__ cnt,
                                                  int* __restrict__ off,
                                                  int* __restrict__ tot) {
  __shared__ int sh[256];
  int b = blockIdx.x, t = threadIdx.x;
  int v[4];
#pragma unroll
  for (int j = 0; j < 4; j++) v[j] = cnt[(t * 4 + j) * NBKT + b];
  int tsum = v[0] + v[1] + v[2] + v[3];
  sh[t] = tsum;
  __syncthreads();
  for (int o = 1; o < 256; o <<= 1) {
    int add = (t >= o) ? sh[t - o] : 0;
    __syncthreads();
    sh[t] += add;
    __syncthreads();
  }
  int p = sh[t] - tsum;
#pragma unroll
  for (int j = 0; j < 4; j++) {
    off[(t * 4 + j) * NBKT + b] = p;
    p += v[j];
  }
  if (t == 255) tot[b] = p;
}

__global__ __launch_bounds__(256) void k_binscanB(const int* __restrict__ tot,
                                                  int* __restrict__ base) {
  __shared__ int sh[256];
  int t = threadIdx.x;
  int v = (t < NBKT) ? tot[t] : 0;
  sh[t] = v;
  __syncthreads();
  for (int o = 1; o < 256; o <<= 1) {
    int add = (t >= o) ? sh[t - o] : 0;
    __syncthreads();
    sh[t] += add;
    __syncthreads();
  }
  if (t < NBKT) base[t] = sh[t] - v;
  if (t == NBKT - 1) base[NBKT] = sh[t];
}

__global__ __launch_bounds__(256) void k_binscat(const int* __restrict__ src,
                                                 const int* __restrict__ dst,
                                                 const int* __restrict__ off,
                                                 const int* __restrict__ base,
                                                 u32* __restrict__ binbuf) {
  __shared__ int posB[NBKT];
  __shared__ int h[NBKT];
  int k = blockIdx.x, t = threadIdx.x;
  for (int i = t; i < NBKT; i += 256) {
    posB[i] = base[i] + off[k * NBKT + i];
    h[i] = 0;
  }
  __syncthreads();
  int e0 = k * EPB;
  int e1 = min(e0 + EPB, N_EDGES);
  for (int e = e0 + t; e < e1; e += 256) {
    u32 d = (u32)dst[e];
    int b = d / (u32)NPB;
    int r = atomicAdd(&h[b], 1);
    binbuf[posB[b] + r] = (u32)src[e] * (u32)NPB + (d - (u32)b * NPB);
  }
}

__global__ __launch_bounds__(256) void k_bdeg(const u32* __restrict__ binbuf,
                                              const int* __restrict__ base,
                                              int* __restrict__ degcnt) {
  __shared__ int c[NPB];
  int b = blockIdx.x, t = threadIdx.x;
  for (int i = t; i < NPB; i += 256) c[i] = 0;
  __syncthreads();
  int s0 = base[b], s1 = base[b + 1];
  for (int i = s0 + t; i < s1; i += 256) {
    u32 p = binbuf[i];
    u32 s = p / (u32)NPB;
    atomicAdd(&c[p - s * (u32)NPB], 1);
  }
  __syncthreads();
  for (int i = t; i < NPB; i += 256) degcnt[b * NPB + i] = c[i];
}

__global__ __launch_bounds__(256) void k_fillB(const u32* __restrict__ binbuf,
                                               const int* __restrict__ base,
                                               const int* __restrict__ row_ptr,
                                               int* __restrict__ col) {
  __shared__ int rp[NPB + 1];
  __shared__ int cur[NPB];
  int b = blockIdx.x, t = threadIdx.x;
  for (int i = t; i < NPB + 1; i += 256) rp[i] = row_ptr[b * NPB + i];
  for (int i = t; i < NPB; i += 256) cur[i] = 0;
  __syncthreads();
  int s0 = base[b], s1 = base[b + 1];
  for (int i = s0 + t; i < s1; i += 256) {
    u32 p = binbuf[i];
    u32 s = p / (u32)NPB;
    int ld = p - s * (u32)NPB;
    int pos = atomicAdd(&cur[ld], 1);
    col[rp[ld] + pos] = (int)s;
  }
  __syncthreads();
  for (int ld = t; ld < NPB; ld += 256) {
    int bs = rp[ld], len = rp[ld + 1] - bs, c = cur[ld];
    for (int j = c; j < len; j++) col[bs + j] = ZROW;
  }
}

// ---------------- GEMMs via MFMA 16x16x32 f16 (W in register B-frags) ----------------

__global__ __launch_bounds__(256) void k_gemm1(const float* __restrict__ x,
                                               const float* __restrict__ W1,
                                               const float* __restrict__ dis,
                                               u16* __restrict__ hs1) {
  int wid = (blockIdx.x * 256 + threadIdx.x) >> 6;   // wave id = 16-row tile
  if (wid >= NTILE) return;
  int l = threadIdx.x & 63;
  int m = l & 15, q = l >> 4;
  f16x8 B[4][2];
#pragma unroll
  for (int s = 0; s < 4; ++s)
#pragma unroll
    for (int h = 0; h < 2; ++h)
#pragma unroll
      for (int j = 0; j < 8; ++j)
        B[s][h][j] = (f16)W1[(s * 32 + q * 8 + j) * EMB + h * 16 + m];
  int row = wid * 16 + m;
  const float* xr = x + (size_t)row * FEAT + q * 8;
  f32x4 acc0 = {0.f, 0.f, 0.f, 0.f}, acc1 = {0.f, 0.f, 0.f, 0.f};
#pragma unroll
  for (int s = 0; s < 4; ++s) {
    f32x4 xa = __builtin_nontemporal_load((const f32x4*)(xr + s * 32));
    f32x4 xb = __builtin_nontemporal_load((const f32x4*)(xr + s * 32 + 4));
    f16x8 A;
    A[0] = (f16)xa.x; A[1] = (f16)xa.y; A[2] = (f16)xa.z; A[3] = (f16)xa.w;
    A[4] = (f16)xb.x; A[5] = (f16)xb.y; A[6] = (f16)xb.z; A[7] = (f16)xb.w;
    acc0 = __builtin_amdgcn_mfma_f32_16x16x32_f16(A, B[s][0], acc0, 0, 0, 0);
    acc1 = __builtin_amdgcn_mfma_f32_16x16x32_f16(A, B[s][1], acc1, 0, 0, 0);
  }
  f32x4 dq = *(const f32x4*)(dis + wid * 16 + q * 4);
  u16* o = hs1 + (size_t)(wid * 16) * EMB;
#pragma unroll
  for (int i = 0; i < 4; ++i) {
    int r = q * 4 + i;
    float dv = (i == 0) ? dq.x : (i == 1) ? dq.y : (i == 2) ? dq.z : dq.w;
    o[(size_t)r * EMB + m]      = __half_as_ushort(__float2half_rn(acc0[i] * dv));
    o[(size_t)r * EMB + 16 + m] = __half_as_ushort(__float2half_rn(acc1[i] * dv));
  }
}

__global__ __launch_bounds__(256) void k_gemm2(const u16* __restrict__ in1,
                                               const float* __restrict__ W2,
                                               const float* __restrict__ dis,
                                               u16* __restrict__ hs2) {
  int wid = (blockIdx.x * 256 + threadIdx.x) >> 6;
  if (wid >= NTILE) return;
  int l = threadIdx.x & 63;
  int m = l & 15, q = l >> 4;
  f16x8 B[2];
#pragma unroll
  for (int h = 0; h < 2; ++h)
#pragma unroll
    for (int j = 0; j < 8; ++j)
      B[h][j] = (f16)W2[(q * 8 + j) * EMB + h * 16 + m];
  int row = wid * 16 + m;
  f16x8 A = *(const f16x8*)(in1 + (size_t)row * EMB + q * 8);
  f32x4 acc0 = {0.f, 0.f, 0.f, 0.f}, acc1 = {0.f, 0.f, 0.f, 0.f};
  acc0 = __builtin_amdgcn_mfma_f32_16x16x32_f16(A, B[0], acc0, 0, 0, 0);
  acc1 = __builtin_amdgcn_mfma_f32_16x16x32_f16(A, B[1], acc1, 0, 0, 0);
  f32x4 dq = *(const f32x4*)(dis + wid * 16 + q * 4);
  u16* o = hs2 + (size_t)(wid * 16) * EMB;
#pragma unroll
  for (int i = 0; i < 4; ++i) {
    int r = q * 4 + i;
    float dv = (i == 0) ? dq.x : (i == 1) ? dq.y : (i == 2) ? dq.z : dq.w;
    o[(size_t)r * EMB + m]      = __half_as_ushort(__float2half_rn(acc0[i] * dv));
    o[(size_t)r * EMB + 16 + m] = __half_as_ushort(__float2half_rn(acc1[i] * dv));
  }
}

// ---------------- Aggregation: 8 lanes per node, shuffle-free, deep-pipelined ----------------
// R13 lesson: feature-split for L2 residency was NULL (agg 46us either way, HBM 12.5%,
// VALU 50%) -> agg is per-wave-overhead + latency-chain bound, NOT L2-miss-BW bound.
// Dense-work floor is ~2us issue + ~5us L2 BW; we're 8x above it with 100K short waves.
// R14 design: 8 nodes per wave (8 lanes/node, sub=l&7 owns 4 dims). Each lane walks its
// node's padded slot list 8 at a time (pad8 guarantees ZROW-padded full blocks -> no
// per-slot bounds checks), 8 gathers + 1 int4 col prefetch in flight per lane. agg1 has
// ZERO cross-lane ops: the node's 8 lanes hold the full 32-dim accumulator and store 8B
// each. 4x fewer waves, amortized prologue, parallel stores.

__device__ __forceinline__ void acc4(float4& A, u16x4 v) {
  float4 f = h4_to_f4(v);
  A.x += f.x; A.y += f.y; A.z += f.z; A.w += f.w;
}

__device__ __forceinline__ float4 agg_node(const u16* __restrict__ hs,
                                           const int* __restrict__ row_ptr,
                                           const int* __restrict__ col,
                                           int node, int sub) {
  const u16x4* t4 = (const u16x4*)hs;
  int a0 = row_ptr[node];
  int na = row_ptr[node + 1] - a0;          // padded degree, multiple of 8, 8-aligned a0
  const int* cp = col + a0;
  int4 c0 = *(const int4*)cp;               // slots 0..3 (safe: within ws even if na==0)
  int4 c1 = *(const int4*)(cp + 4);         // slots 4..7
  float4 A = make_float4(0.f, 0.f, 0.f, 0.f);
  for (int i = 0; i < na; i += 8) {
    u16x4 v0 = t4[(size_t)c0.x * 8 + sub];
    u16x4 v1 = t4[(size_t)c0.y * 8 + sub];
    u16x4 v2 = t4[(size_t)c0.z * 8 + sub];
    u16x4 v3 = t4[(size_t)c0.w * 8 + sub];
    u16x4 v4 = t4[(size_t)c1.x * 8 + sub];
    u16x4 v5 = t4[(size_t)c1.y * 8 + sub];
    u16x4 v6 = t4[(size_t)c1.z * 8 + sub];
    u16x4 v7 = t4[(size_t)c1.w * 8 + sub];
    if (i + 8 < na) {                       // prefetch next col block
      c0 = *(const int4*)(cp + i + 8);
      c1 = *(const int4*)(cp + i + 12);
    }
    acc4(A, v0); acc4(A, v1); acc4(A, v2); acc4(A, v3);
    acc4(A, v4); acc4(A, v5); acc4(A, v6); acc4(A, v7);
  }
  // self-loop contribution (row pre-scaled by dis[node] at GEMM time)
  acc4(A, t4[(size_t)node * 8 + sub]);
  return A;
}

__device__ __forceinline__ float4 relu_row(float4 acc, float d, float4 bq) {
  float4 o;
  o.x = fmaxf(fmaf(acc.x, d, bq.x), 0.f);
  o.y = fmaxf(fmaf(acc.y, d, bq.y), 0.f);
  o.z = fmaxf(fmaf(acc.z, d, bq.z), 0.f);
  o.w = fmaxf(fmaf(acc.w, d, bq.w), 0.f);
  return o;
}

// grid = N_NODES/32 blocks; wave handles 8 nodes, lane group (l>>3) one node
__global__ __launch_bounds__(256) void k_agg1(const u16* __restrict__ hs,
                                              const int* __restrict__ row_ptr,
                                              const int* __restrict__ col,
                                              const float* __restrict__ dis,
                                              const float* __restrict__ b,
                                              u16* __restrict__ out) {
  int t = threadIdx.x;
  int l = t & 63;
  int node = blockIdx.x * 32 + (t >> 6) * 8 + (l >> 3);
  int sub = l & 7;
  float4 A = agg_node(hs, row_ptr, col, node, sub);
  float4 bq = ((const float4*)b)[sub];
  float4 o = relu_row(A, dis[node], bq);
  ((u16x4*)(out + (size_t)node * EMB))[sub] = f4_to_h4(o);
}

__global__ __launch_bounds__(256) void k_agg2pool(const u16* __restrict__ hs,
                                                  const int* __restrict__ row_ptr,
                                                  const int* __restrict__ col,
                                                  const float* __restrict__ dis,
                                                  const float* __restrict__ b2,
                                                  const float* __restrict__ Wo,
                                                  const int* __restrict__ batch,
                                                  float* __restrict__ gaccP) {
  int t = threadIdx.x;
  int l = t & 63;
  int node = blockIdx.x * 32 + (t >> 6) * 8 + (l >> 3);
  int sub = l & 7;
  float4 A = agg_node(hs, row_ptr, col, node, sub);
  float4 bq = ((const float4*)b2)[sub];
  float4 wq = ((const float4*)Wo)[sub];
  float4 o = relu_row(A, dis[node], bq);
  float p = o.x * wq.x + o.y * wq.y + o.z * wq.z + o.w * wq.w;
  p += __shfl_xor(p, 1);
  p += __shfl_xor(p, 2);
  p += __shfl_xor(p, 4);
  if (sub == 0)
    atomicAdd(&gaccP[(node & (NCOPY - 1)) * N_GRAPHS + batch[node]], p);
}

__global__ __launch_bounds__(256) void k_finalize(const float* __restrict__ gaccP,
                                                  const int* __restrict__ gcnt,
                                                  const float* __restrict__ bo,
                                                  float* __restrict__ out) {
  int g = blockIdx.x * 256 + threadIdx.x;
  if (g < N_GRAPHS) {
    float s = 0.f;
#pragma unroll 8
    for (int c = 0; c < NCOPY; ++c) s += gaccP[c * N_GRAPHS + g];
    out[g] = s / fmaxf((float)gcnt[g], 1.0f) + bo[0];
  }
}

// ---------------- launch ----------------

extern "C" void kernel_launch(void* const* d_in, const int* in_sizes, int n_in,
                              void* d_out, int out_size, void* d_ws, size_t ws_size,
                              hipStream_t stream) {
  const float* x     = (const float*)d_in[0];
  const int*   ei    = (const int*)d_in[1];   // [2, E]: src then dst
  const int*   batch = (const int*)d_in[2];
  const float* W1    = (const float*)d_in[3];
  const float* b1    = (const float*)d_in[4];
  const float* W2    = (const float*)d_in[5];
  const float* b2    = (const float*)d_in[6];
  const float* Wo    = (const float*)d_in[7];
  const float* bo    = (const float*)d_in[8];
  float* out = (float*)d_out;

  const int* src = ei;
  const int* dst = ei + N_EDGES;

  char* w = (char*)d_ws;
  float* gaccP   = (float*)w;  w += (size_t)NCOPY * N_GRAPHS * 4;   // zeroed
  size_t zero_bytes = (size_t)(w - (char*)d_ws);
  int*   degcnt  = (int*)w;    w += (size_t)N_NODES * 4;            // written by k_bdeg
  int*   gcnt    = (int*)w;    w += (size_t)N_GRAPHS * 4;
  int*   row_ptr = (int*)w;    w += (size_t)(N_NODES + 4) * 4;
  int*   blocksum= (int*)w;    w += 128 * 4;
  int*   blockoff= (int*)w;    w += 128 * 4;
  int*   cnt     = (int*)w;    w += (size_t)ABLK * NBKT * 4;        // 1.0 MB
  int*   boff    = (int*)w;    w += (size_t)ABLK * NBKT * 4;        // 1.0 MB
  int*   btot    = (int*)w;    w += (size_t)(NBKT + 8) * 4;
  int*   bbase   = (int*)w;    w += (size_t)(NBKT + 8) * 4;
  int*   col     = (int*)w;    w += (size_t)PADCAP * 4;
  float* dis     = (float*)w;  w += (size_t)N_NODES * 4;
  u16*   hs1     = (u16*)w;    w += (size_t)(N_NODES + 1) * EMB * 2;  // +1 zero row
  u16*   out1    = (u16*)w;    w += (size_t)N_NODES * EMB * 2;        // 6.4 MB
  u32*   binbuf  = (u32*)out1;  // alias: binbuf dead before agg1 writes out1
  u16*   hs2     = hs1;         // hs1 dead after agg1; zero row persists

  const int NB  = (N_NODES + 255) / 256;    // 391
  const int SB  = (N_NODES + 1023) / 1024;  // 98
  const int GB  = (NTILE * 64 + 255) / 256; // 1563 MFMA blocks

  (void)hipMemsetAsync(d_ws, 0, zero_bytes, stream);

  // bin pipeline (produces binbuf + degree histogram)
  k_binA<<<ABLK, 256, 0, stream>>>(dst, cnt);
  k_binscanA<<<NBKT, 256, 0, stream>>>(cnt, boff, btot);
  k_binscanB<<<1, 256, 0, stream>>>(btot, bbase);
  k_binscat<<<ABLK, 256, 0, stream>>>(src, dst, boff, bbase, binbuf);
  k_bdeg<<<NBKT, 256, 0, stream>>>(binbuf, bbase, degcnt);

  k_node_init<<<NB, 256, 0, stream>>>(degcnt, dis, hs1);
  k_gcnt<<<1, 512, 0, stream>>>(batch, gcnt);
  k_scanA<<<SB, 256, 0, stream>>>(degcnt, blocksum);
  k_scanB<<<1, 128, 0, stream>>>(blocksum, blockoff, row_ptr + N_NODES, SB);
  k_scanC<<<SB, 256, 0, stream>>>(degcnt, blockoff, row_ptr);
  k_fillB<<<NBKT, 256, 0, stream>>>(binbuf, bbase, row_ptr, col);

  k_gemm1<<<GB, 256, 0, stream>>>(x, W1, dis, hs1);
  k_agg1<<<AGB, 256, 0, stream>>>(hs1, row_ptr, col, dis, b1, out1);
  k_gemm2<<<GB, 256, 0, stream>>>(out1, W2, dis, hs2);
  k_agg2pool<<<AGB, 256, 0, stream>>>(hs2, row_ptr, col, dis, b2, Wo, batch, gaccP);
  k_finalize<<<2, 256, 0, stream>>>(gaccP, gcnt, bo, out);
}